// Round 8
// baseline (116.206 us; speedup 1.0000x reference)
//
#include <hip/hip_runtime.h>
#include <cstdint>

typedef unsigned long long u64;
typedef unsigned int u32;

#define NB 4096
#define NW 64            // 64-bit words per mask row
#define MM 20
#define HH 16
#define COND_THRES 0.2f
#define IOU_THRES 0.3f
#define PI_F  3.14159265358979323846f
#define PI4_F 0.78539816339744830962f

#define NTILE 2080       // lower-triangle 64x64 tiles
#define MASK_BLOCKS 130  // 16 tiles per block (130*16 == 2080)

// ---- workspace layout (bytes) ----
#define WS_DONE    0                           // u32 done-counter (last-block detection)
#define WS_MASK    32768                       // u64[NB*NW] = 2 MiB
#define WS_BOX9S   (WS_MASK + NB*NW*8)         // float[NB*9]
#define WS_BEVS    (WS_BOX9S + NB*9*4)         // float4[NB]
#define WS_SCORES  (WS_BEVS + NB*16)           // float[NB]
#define WS_LABELS  (WS_SCORES + NB*4)          // int[NB]
#define WS_NBRW    (WS_LABELS + NB*4)          // u64[NB]
#define WS_SUPSTEP (WS_NBRW + NB*8)            // int[NB]

__device__ __forceinline__ u64 sort_key(float s, int i) {
  u32 sb = (s > COND_THRES) ? __float_as_uint(s) : 0u;
  return ((u64)(sb ^ 0xFFFFFFFFu) << 12) | (u64)i;
}

// ---------- K1: fused counting-rank + scatter + BEV (verbatim round-7, passed).
// Also resets nbrw and the done-counter (device atomic -> coherence point).
__global__ void __launch_bounds__(256) k_prep(const float* __restrict__ scores,
                                              const float* __restrict__ boxes9,
                                              const int* __restrict__ labels,
                                              float* __restrict__ box9s, float4* __restrict__ bevs,
                                              float* __restrict__ scoress, int* __restrict__ labelss,
                                              u64* __restrict__ nbrw, u32* __restrict__ doneCnt) {
  #pragma clang fp contract(off)
  __shared__ u64 keys[NB];        // 32 KB
  __shared__ u32 part[16][16];
  int tid = threadIdx.x;
  for (int k = tid; k < NB; k += 256) keys[k] = sort_key(scores[k], k);
  if (blockIdx.x == 0 && tid == 0) atomicExch(doneCnt, 0u);
  __syncthreads();
  int bl = tid & 15;              // box-local 0..15
  int ch = tid >> 4;              // chunk 0..15 (256 keys each)
  u64 ki = keys[blockIdx.x * 16 + bl];
  int c = 0;
  #pragma unroll 16
  for (int t = 0; t < 256; ++t) c += (keys[(ch << 8) + t] < ki) ? 1 : 0;  // LDS broadcast
  part[bl][ch] = (u32)c;
  __syncthreads();
  if (tid < 16) {
    int i = blockIdx.x * 16 + tid;
    int r = 0;
    #pragma unroll
    for (int q = 0; q < 16; ++q) r += (int)part[tid][q];
    nbrw[i] = 0;
    float b[9];
    #pragma unroll
    for (int f = 0; f < 9; ++f) b[f] = boxes9[i * 9 + f];
    #pragma unroll
    for (int f = 0; f < 9; ++f) box9s[r * 9 + f] = b[f];
    float ang = b[6] - floorf(b[6] / PI_F + 0.5f) * PI_F;
    bool sw = fabsf(ang) >= PI4_F;
    float dx = sw ? b[4] : b[3];
    float dy = sw ? b[3] : b[4];
    bevs[r] = make_float4(b[0] - dx * 0.5f, b[1] - dy * 0.5f,
                          b[0] + dx * 0.5f, b[1] + dy * 0.5f);
    scoress[r] = scores[i];
    labelss[r] = labels[i];
  }
}

// ---------- K2: pairwise over-matrix (symmetric-halved, 16 tiles/block) FUSED
// with NMS+supstep via the "last block continues" pattern (zero polling).
// Each block: 16 triangular tiles (one per wave; IOU/transpose math verbatim
// round-7, barriers hoisted to uniform block scope). Then: release fence +
// done-counter; ONLY the last-finishing block acquire-fences and runs the
// round-7 NMS + supstep body with its 1024 threads. No block ever spins.
__global__ void __launch_bounds__(1024) k_masknms(
    const float4* __restrict__ bevs, const int* __restrict__ labelss,
    const float* __restrict__ scoress,
    u64* __restrict__ mask, u64* __restrict__ nbrw,
    const u64* __restrict__ nbrw_c, int* __restrict__ supstep,
    u32* __restrict__ doneCnt) {
  #pragma clang fp contract(off)
  __shared__ float4 bj[16][64];   // 16 KB
  __shared__ int    lj[16][64];   // 4 KB
  __shared__ u64    tw[16][64];   // 8 KB
  __shared__ u64 decided[64], kept[64];
  __shared__ int wavePending[16];
  __shared__ int isLast;
  const int tid = threadIdx.x;
  const int lane = tid & 63;
  const int waveId = tid >> 6;

  // ===== mask phase: tile T per wave =====
  {
    int T = (blockIdx.x << 4) | waveId;     // 0..2079, exactly NTILE tiles
    // triangular decode: largest it with it*(it+1)/2 <= T (float est + exact fix)
    int it = (int)((sqrtf(8.0f * (float)T + 1.0f) - 1.0f) * 0.5f);
    while ((it + 1) * (it + 2) / 2 <= T) ++it;
    while (it * (it + 1) / 2 > T) --it;
    int jt = T - it * (it + 1) / 2;
    int j = jt * 64 + lane;
    bj[waveId][lane] = bevs[j];
    lj[waveId][lane] = labelss[j];
    u64 vj = __ballot(scoress[j] > COND_THRES);   // valid mask of this j-tile
    int i = it * 64 + lane;
    float4 a = bevs[i];
    int la = labelss[i];
    float area_a = (a.z - a.x) * (a.w - a.y);
    __syncthreads();                              // uniform (all 16 waves)
    u64 w = 0;
    #pragma unroll 8
    for (int kk = 0; kk < 64; ++kk) {
      float4 bb = bj[waveId][kk];
      float xmin = fmaxf(a.x, bb.x), ymin = fmaxf(a.y, bb.y);
      float xmax = fminf(a.z, bb.z), ymax = fminf(a.w, bb.w);
      float inter = fmaxf(xmax - xmin, 0.0f) * fmaxf(ymax - ymin, 0.0f);
      float area_b = (bb.z - bb.x) * (bb.w - bb.y);
      float iou = inter / fmaxf(area_a + area_b - inter, 1e-6f);
      if ((iou > IOU_THRES) && (la == lj[waveId][kk])) w |= (1ull << kk);
    }
    mask[(u64)i * NW + jt] = w;
    {
      u64 below = (jt < it) ? ~0ull : ((1ull << lane) - 1ull);
      if (w & vj & below) atomicOr(&nbrw[i], 1ull << jt);
    }
    tw[waveId][lane] = w;
    __syncthreads();                              // uniform
    if (jt < it) {
      // transposed tile: row j = jt*64+lane, word it; bit k = bit lane of lane k's w
      u64 wT = 0;
      #pragma unroll 8
      for (int k = 0; k < 64; ++k) wT |= ((tw[waveId][k] >> lane) & 1ull) << k;
      mask[(u64)j * NW + it] = wT;
    }
  }

  // ===== last-block detection (no polling) =====
  __syncthreads();   // all waves' stores drained (waitcnt before barrier)
  if (tid == 0) {
    __builtin_amdgcn_fence(__ATOMIC_RELEASE, "agent");  // wb this XCD's L2
    u32 v = atomicAdd(doneCnt, 1u);
    int last = (v == (u32)(MASK_BLOCKS - 1));
    if (last) __builtin_amdgcn_fence(__ATOMIC_ACQUIRE, "agent"); // inv stale L2
    isLast = last;
  }
  __syncthreads();
  if (!isLast) return;

  // ===== NMS + supstep (verbatim round-7 body; 1024 threads) =====
  bool validB[4];
  #pragma unroll
  for (int s = 0; s < 4; ++s) {
    int i = tid + (s << 10);
    bool v = scoress[i] > COND_THRES;
    validB[s] = v;
    u64 vw = __ballot(v);
    if (lane == 0) {
      decided[waveId + (s << 4)] = ~vw;   // invalids pre-decided, not kept
      kept[waveId + (s << 4)] = 0;
    }
  }
  u64 cw0[4], cw1[4];
  u32 meta[4];   // [5:0] idx0, [11:6] idx1, [13:12] n(min 2), [14] overflow
  #pragma unroll
  for (int s = 0; s < 4; ++s) {
    int i = tid + (s << 10);
    int wi = i >> 6;
    u64 bit = 1ull << (i & 63);
    u64 t = nbrw_c[i];
    int n = 0; u32 ovf = 0;
    u64 c0 = 0, c1 = 0; u32 i0 = 0, i1 = 0;
    while (t) {
      int w = __builtin_ctzll(t);
      t &= t - 1;
      u64 below = (w < wi) ? ~0ull : (bit - 1ull);
      u64 m = mask[(u64)i * NW + w] & below;
      if (n == 0)      { c0 = m; i0 = (u32)w; }
      else if (n == 1) { c1 = m; i1 = (u32)w; }
      else ovf = 1;
      ++n;
    }
    cw0[s] = c0; cw1[s] = c1;
    meta[s] = i0 | (i1 << 6) | ((u32)(n > 2 ? 2 : n) << 12) | (ovf << 14);
  }
  __syncthreads();
  // ordered segment passes (Gauss-Seidel)
  for (int s = 0; s < 4; ++s) {
    const int i = tid + (s << 10);
    const int wi = waveId + (s << 4);
    const u64 bit = 1ull << (i & 63);
    const u32 mt = meta[s];
    bool und = validB[s];
    while (true) {
      bool dec = false, keepme = false;
      if (und) {
        bool hasU = false, hasK = false;
        if (!(mt & (1u << 14))) {
          int n = (mt >> 12) & 3;
          if (n >= 1) {
            int w = mt & 63;
            u64 dw = decided[w], kw = kept[w];
            hasU = (cw0[s] & ~dw) != 0ull;
            hasK = (cw0[s] & kw) != 0ull;
          }
          if (n >= 2) {
            int w = (mt >> 6) & 63;
            u64 dw = decided[w], kw = kept[w];
            hasU = hasU || ((cw1[s] & ~dw) != 0ull);
            hasK = hasK || ((cw1[s] & kw) != 0ull);
          }
        } else {
          u64 t = nbrw_c[i];
          while (t) {
            int w = __builtin_ctzll(t);
            t &= t - 1;
            u64 below = (w < wi) ? ~0ull : (bit - 1ull);
            u64 m = mask[(u64)i * NW + w] & below;
            hasU = hasU || ((m & ~decided[w]) != 0ull);
            hasK = hasK || ((m & kept[w]) != 0ull);
          }
        }
        dec = !hasU;
        keepme = !hasK;
      }
      u64 b_nd = __ballot(dec);
      u64 b_nk = __ballot(dec && keepme);
      bool pend = und && !dec;
      u64 pw = __ballot(pend);
      if (lane == 0) {
        decided[wi] |= b_nd;               // wave exclusively owns word wi
        kept[wi] |= b_nk;
        wavePending[waveId] = (pw != 0ull) ? 1 : 0;
      }
      und = pend;
      __syncthreads();
      int any = 0;
      #pragma unroll
      for (int w = 0; w < 16; ++w) any |= wavePending[w];   // LDS broadcast
      if (!any) break;
    }
  }
  // supstep from cache (kept[] final in LDS)
  #pragma unroll
  for (int s = 0; s < 4; ++s) {
    int j = tid + (s << 10);
    int res;
    if (!validB[s]) {
      res = -1;
    } else {
      res = j;                       // no earlier kept claimant -> j itself kept
      u32 mt = meta[s];
      if (!(mt & (1u << 14))) {
        int n = (mt >> 12) & 3;
        if (n >= 1) {
          int w0 = mt & 63;
          u64 m0 = cw0[s] & kept[w0];
          if (m0) {
            res = (w0 << 6) + __builtin_ctzll(m0);          // min word, min bit
          } else if (n >= 2) {
            int w1 = (mt >> 6) & 63;
            u64 m1 = cw1[s] & kept[w1];
            if (m1) res = (w1 << 6) + __builtin_ctzll(m1);
          }
        }
      } else {
        // rare (>2 words): global re-scan, words ascending -> min claimant
        int wj = j >> 6;
        u64 bitbelow = (1ull << (j & 63)) - 1ull;
        u64 t = nbrw_c[j];
        while (t) {
          int w = __builtin_ctzll(t);
          t &= t - 1;
          u64 m = mask[(u64)j * NW + w] & kept[w];
          if (w == wj) m &= bitbelow;
          if (m) { res = (w << 6) + __builtin_ctzll(m); break; }
        }
      }
    }
    supstep[j] = res;
  }
}

// ---------- K3: per-box merge + all outputs (verbatim round-7, passed).
__global__ void __launch_bounds__(64) k_merge(
    const u64* __restrict__ mask, const int* __restrict__ supstep,
    const float* __restrict__ box9s, const float* __restrict__ scoress,
    const int* __restrict__ labelss,
    const float* __restrict__ w1, const float* __restrict__ b1,
    const float* __restrict__ w2, const float* __restrict__ b2,
    const float* __restrict__ w3, const float* __restrict__ b3,
    float* __restrict__ out) {
  #pragma clang fp contract(off)
  __shared__ int candList[MM];
  __shared__ float ob[MM][7];
  __shared__ float h1[7][HH];
  __shared__ float h2[7][HH];
  __shared__ float res[7];
  int i = blockIdx.x;
  int t = threadIdx.x;
  bool active = (supstep[i] == i);
  u64 wq = 0;
  int cnt = 0;
  if (active) {
    u64 w = mask[(u64)i * NW + t];
    while (w) {
      int b = __builtin_ctzll(w);
      w &= w - 1;
      int j = (t << 6) | b;
      if (supstep[j] >= i) { wq |= (1ull << b); cnt++; }
    }
  }
  int incl = cnt;
  #pragma unroll
  for (int off = 1; off < 64; off <<= 1) {
    int v = __shfl_up(incl, off);
    if (t >= off) incl += v;
  }
  int excl = incl - cnt;
  int count = __shfl(incl, 63);
  bool merged = active && (count > 1);
  if (merged && wq) {
    int pos = excl;
    u64 ww = wq;
    while (ww && pos < MM) {
      int b = __builtin_ctzll(ww);
      ww &= ww - 1;
      candList[pos++] = (t << 6) | b;
    }
  }
  __syncthreads();
  if (merged) {
    int nc = count < MM ? count : MM;
    if (t < MM) {
      if (t < nc) {
        int j = candList[t];
        #pragma unroll
        for (int f = 0; f < 7; ++f) ob[t][f] = box9s[j * 9 + f];
      } else {
        #pragma unroll
        for (int f = 0; f < 7; ++f) ob[t][f] = 0.0f;
      }
    }
    __syncthreads();
    for (int o = t; o < 7 * HH; o += 64) {
      int f = o >> 4, hh = o & 15;
      float acc = b1[hh];
      #pragma unroll
      for (int m = 0; m < MM; ++m) acc += ob[m][f] * w1[m * HH + hh];
      h1[f][hh] = fmaxf(acc, 0.0f);
    }
    __syncthreads();
    for (int o = t; o < 7 * HH; o += 64) {
      int f = o >> 4, oo = o & 15;
      float acc = b2[oo];
      #pragma unroll
      for (int k = 0; k < HH; ++k) acc += h1[f][k] * w2[k * HH + oo];
      h2[f][oo] = fmaxf(acc, 0.0f);
    }
    __syncthreads();
    if (t < 7) {
      float acc = b3[0];
      #pragma unroll
      for (int k = 0; k < HH; ++k) acc += h2[t][k] * w3[k];
      if (t >= 3 && t < 6) acc = fmaxf(acc, 1e-5f);
      res[t] = acc;
    }
    __syncthreads();
  }
  if (t < 9) {
    float v = box9s[i * 9 + t];
    if (merged && t < 7) v = res[t];
    out[i * 9 + t] = v;
  }
  if (t == 0) {
    out[NB * 9 + i]          = scoress[i];
    out[NB * 9 + NB + i]     = (float)labelss[i];
    out[NB * 9 + 2 * NB + i] = active ? 1.0f : 0.0f;
  }
}

extern "C" void kernel_launch(void* const* d_in, const int* in_sizes, int n_in,
                              void* d_out, int out_size, void* d_ws, size_t ws_size,
                              hipStream_t stream) {
  const float* boxes9 = (const float*)d_in[0];
  const float* scores = (const float*)d_in[1];
  const int*   labels = (const int*)d_in[2];
  const float* w1 = (const float*)d_in[3];
  const float* b1 = (const float*)d_in[4];
  const float* w2 = (const float*)d_in[5];
  const float* b2 = (const float*)d_in[6];
  const float* w3 = (const float*)d_in[7];
  const float* b3 = (const float*)d_in[8];
  char* ws = (char*)d_ws;
  u32*    doneCnt = (u32*)(ws + WS_DONE);
  u64*    mask    = (u64*)(ws + WS_MASK);
  float*  box9s   = (float*)(ws + WS_BOX9S);
  float4* bevs    = (float4*)(ws + WS_BEVS);
  float*  scoress = (float*)(ws + WS_SCORES);
  int*    labelss = (int*)(ws + WS_LABELS);
  u64*    nbrw    = (u64*)(ws + WS_NBRW);
  int*    supstep = (int*)(ws + WS_SUPSTEP);
  float*  out     = (float*)d_out;

  hipLaunchKernelGGL(k_prep,    dim3(256),         dim3(256),  0, stream,
                     scores, boxes9, labels, box9s, bevs, scoress, labelss, nbrw, doneCnt);
  hipLaunchKernelGGL(k_masknms, dim3(MASK_BLOCKS), dim3(1024), 0, stream,
                     bevs, labelss, scoress, mask, nbrw, nbrw, supstep, doneCnt);
  hipLaunchKernelGGL(k_merge,   dim3(NB),          dim3(64),   0, stream,
                     mask, supstep, box9s, scoress, labelss,
                     w1, b1, w2, b2, w3, b3, out);
}